// Round 4
// baseline (1085.980 us; speedup 1.0000x reference)
//
#include <hip/hip_runtime.h>

#define NN 50000
#define EE 800000
#define BB 4096
#define SCAN_BLK 49   // ceil(50000/1024)
#define BW 98         // bucket node-width
#define NB 512        // buckets (512*98 >= 50000)

// f32 weight-table offsets (elements)
#define OFF_T1W 0
#define OFF_T1B 16384
#define OFF_GW1 16448
#define OFF_GB1 16832
#define OFF_HW1 16848
#define OFF_GW2 29136
#define OFF_GB2 30288
#define OFF_HW2 30304
#define OFF_T2W 67168
#define OFF_T2B 112224
#define OFF_T3W 112288
#define OFF_T3B 112416
#define WTOT    112418

// bf16 weight table (MFMA B-operands)
#define WB_T1W  0        // t1w native [64][256]
#define WB_HW1T 16384    // 3 x hw1^T [64][64]
#define WB_HW2T 28672    // 3 x hw2^T [64][192]
#define WB_T2W  65536    // t2w native [64][704]
#define WB_TOT  110592

typedef __attribute__((ext_vector_type(8))) short bf16x8;
typedef __attribute__((ext_vector_type(4))) float f32x4;

__device__ __forceinline__ float bf2f(unsigned short u) {
    return __uint_as_float(((unsigned int)u) << 16);
}
__device__ __forceinline__ unsigned short f2bf(float f) {
    unsigned int u = __float_as_uint(f);
    u = (u + 0x7fffu + ((u >> 16) & 1u)) >> 16;
    return (unsigned short)u;
}
__device__ __forceinline__ float leakyf(float v) { return v >= 0.f ? v : 0.3f * v; }
__device__ __forceinline__ float tanh_fast(float v) {
    float e = __expf(2.f * v);
    return 1.f - 2.f / (e + 1.f);
}
__device__ __forceinline__ int rfl(int v) { return __builtin_amdgcn_readfirstlane(v); }

// ---------- dtype sniffer: 0 = bf16, 1 = f32 ----------
__global__ void k_sniff(const unsigned short* __restrict__ hs, int* __restrict__ flag) {
    int lane = threadIdx.x;
    unsigned short s = hs[2 * lane];
    int ef = (s >> 7) & 0xFF;
    unsigned long long m = __ballot(ef >= 100 && ef <= 132);
    if (lane == 0) flag[0] = (__popcll(m) >= 40) ? 0 : 1;
}

// ---------- convert all weight tensors to one f32 table ----------
__global__ __launch_bounds__(1024) void k_convert(
    const int* __restrict__ fl,
    const void* t1w, const void* t1b,
    const void* gw1a, const void* gw1b, const void* gw1c,
    const void* gb1a, const void* gb1b, const void* gb1c,
    const void* hw1a, const void* hw1b, const void* hw1c,
    const void* gw2a, const void* gw2b, const void* gw2c,
    const void* gb2a, const void* gb2b, const void* gb2c,
    const void* hw2a, const void* hw2b, const void* hw2c,
    const void* t2w, const void* t2b, const void* t3w, const void* t3b,
    float* __restrict__ fw) {
    const int starts[24] = {0, 16384, 16448, 16576, 16704, 16832, 16833, 16834,
                            16848, 20944, 25040, 29136, 29520, 29904, 30288, 30289, 30290,
                            30304, 42592, 54880, 67168, 112224, 112288, 112416};
    const int cnts[24] = {16384, 64, 128, 128, 128, 1, 1, 1, 4096, 4096, 4096,
                          384, 384, 384, 1, 1, 1, 12288, 12288, 12288, 45056, 64, 128, 2};
    const void* sp[24] = {t1w, t1b, gw1a, gw1b, gw1c, gb1a, gb1b, gb1c, hw1a, hw1b, hw1c,
                          gw2a, gw2b, gw2c, gb2a, gb2b, gb2c, hw2a, hw2b, hw2c, t2w, t2b, t3w, t3b};
    int isf32 = fl[0];
    int idx = blockIdx.x * 1024 + threadIdx.x;
    if (idx >= WTOT) return;
    float v = 0.f;
#pragma unroll
    for (int k = 0; k < 24; ++k) {
        int lo = idx - starts[k];
        if (lo >= 0 && lo < cnts[k])
            v = isf32 ? ((const float*)sp[k])[lo] : bf2f(((const unsigned short*)sp[k])[lo]);
    }
    fw[idx] = v;
}

// ---------- bf16 weight table: t1w, hw1^T, hw2^T, t2w ----------
__global__ __launch_bounds__(256) void k_convert16(const int* __restrict__ fl, const void* t1w,
                                                   const void* hw1a, const void* hw1b, const void* hw1c,
                                                   const void* hw2a, const void* hw2b, const void* hw2c,
                                                   const void* t2w, unsigned short* __restrict__ wb) {
    int idx = blockIdx.x * 256 + threadIdx.x;
    if (idx >= WB_TOT) return;
    int isf32 = fl[0];
    const void* p;
    int srci;
    if (idx < WB_HW1T) {
        p = t1w; srci = idx;
    } else if (idx < WB_HW2T) {
        int rel = idx - WB_HW1T;
        int set = rel >> 12, r2 = rel & 4095;
        int jj = r2 >> 6, kk = r2 & 63;          // hw1T[j][k] = hw1[k][j], [64][64]
        p = set == 0 ? hw1a : (set == 1 ? hw1b : hw1c);
        srci = kk * 64 + jj;
    } else if (idx < WB_T2W) {
        int rel = idx - WB_HW2T;
        int set = rel / 12288, r2 = rel % 12288;
        int n = r2 / 192, k = r2 % 192;          // hw2T[n][k] = hw2[k][n], hw2 [192][64]
        p = set == 0 ? hw2a : (set == 1 ? hw2b : hw2c);
        srci = k * 64 + n;
    } else {
        p = t2w; srci = idx - WB_T2W;            // t2w native [64][704]
    }
    wb[idx] = isf32 ? f2bf(((const float*)p)[srci]) : ((const unsigned short*)p)[srci];
}

// ---------- degree count ----------
__global__ __launch_bounds__(256) void k_deg(const int* __restrict__ d0, const int* __restrict__ d1,
                                             const int* __restrict__ d2, int* __restrict__ deg) {
    int set = blockIdx.y;
    const int* dd = set == 0 ? d0 : (set == 1 ? d1 : d2);
    int t = blockIdx.x * 256 + threadIdx.x;
    if (t < EE) atomicAdd(&deg[(size_t)set * NN + dd[t]], 1);
}

// ---------- d into .z of per-node float4 packs (x=ps, y=pd, z=d) ----------
__global__ __launch_bounds__(256) void k_dnorm(const int* __restrict__ deg, float* __restrict__ g1,
                                               float* __restrict__ g2) {
    int t = blockIdx.x * 256 + threadIdx.x;
    if (t < 3 * NN) {
        int g = deg[t];
        float v = g > 0 ? rsqrtf((float)g) : 0.f;
        g1[(size_t)t * 4 + 2] = v;
        g2[(size_t)t * 4 + 2] = v;
    }
}

// ---------- hierarchical exclusive scan ----------
__global__ __launch_bounds__(256) void k_scan1(const int* __restrict__ deg, int* __restrict__ rowptr,
                                               int* __restrict__ bsum) {
    int set = blockIdx.y;
    const int* dg = deg + (size_t)set * NN;
    int* rp = rowptr + (size_t)set * NN;
    __shared__ int sh[256];
    int tid = threadIdx.x;
    int base = blockIdx.x * 1024 + tid * 4;
    int v[4]; int s = 0;
#pragma unroll
    for (int c = 0; c < 4; ++c) { int idx = base + c; v[c] = (idx < NN) ? dg[idx] : 0; s += v[c]; }
    sh[tid] = s;
    __syncthreads();
    for (int off = 1; off < 256; off <<= 1) {
        int t = 0;
        if (tid >= off) t = sh[tid - off];
        __syncthreads();
        if (tid >= off) sh[tid] += t;
        __syncthreads();
    }
    int run = sh[tid] - s;
#pragma unroll
    for (int c = 0; c < 4; ++c) { int idx = base + c; if (idx < NN) rp[idx] = run; run += v[c]; }
    if (tid == 255) bsum[set * SCAN_BLK + blockIdx.x] = sh[255];
}

__global__ void k_scan2(int* __restrict__ bsum) {
    int set = blockIdx.x;
    int* b = bsum + set * SCAN_BLK;
    if (threadIdx.x == 0) {
        int acc = 0;
        for (int i = 0; i < SCAN_BLK; ++i) { int t = b[i]; b[i] = acc; acc += t; }
    }
}

__global__ __launch_bounds__(256) void k_scan3(int* __restrict__ rowptr, const int* __restrict__ bsum) {
    int set = blockIdx.y;
    int add = bsum[set * SCAN_BLK + blockIdx.x];
    int base = blockIdx.x * 1024 + threadIdx.x * 4;
    int* rp = rowptr + (size_t)set * NN;
#pragma unroll
    for (int c = 0; c < 4; ++c) {
        int idx = base + c;
        if (idx < NN) rp[idx] += add;
    }
}

// ---------- input transform via MFMA: x = leaky(h @ t1w^T + b), fused p1 gate dots ----------
__global__ __launch_bounds__(256) void k_input(const int* __restrict__ fl,
                                               const void* __restrict__ hB,
                                               const unsigned short* __restrict__ wb,
                                               const float* __restrict__ fw,
                                               unsigned short* __restrict__ x16,
                                               float4* __restrict__ g1v4) {
    __shared__ float xt[16][65];
    int tid = threadIdx.x, lane = tid & 63, wid = tid >> 6;
    int m = lane & 15, q = lane >> 4;
    int node0 = blockIdx.x * 16;
    int isf32 = fl[0];
    f32x4 acc = {0.f, 0.f, 0.f, 0.f};
    const unsigned short* bsrc = wb + WB_T1W + ((size_t)(wid * 16 + m)) * 256 + q * 8;
    if (isf32) {
        const float* ap = (const float*)hB + (size_t)(node0 + m) * 256 + q * 8;
        for (int k0 = 0; k0 < 256; k0 += 32) {
            float4 f0 = *(const float4*)(ap + k0);
            float4 f1 = *(const float4*)(ap + k0 + 4);
            bf16x8 a;
            a[0] = (short)f2bf(f0.x); a[1] = (short)f2bf(f0.y);
            a[2] = (short)f2bf(f0.z); a[3] = (short)f2bf(f0.w);
            a[4] = (short)f2bf(f1.x); a[5] = (short)f2bf(f1.y);
            a[6] = (short)f2bf(f1.z); a[7] = (short)f2bf(f1.w);
            bf16x8 b = *(const bf16x8*)(bsrc + k0);
            acc = __builtin_amdgcn_mfma_f32_16x16x32_bf16(a, b, acc, 0, 0, 0);
        }
    } else {
        const unsigned short* ap = (const unsigned short*)hB + (size_t)(node0 + m) * 256 + q * 8;
        for (int k0 = 0; k0 < 256; k0 += 32) {
            bf16x8 a = *(const bf16x8*)(ap + k0);
            bf16x8 b = *(const bf16x8*)(bsrc + k0);
            acc = __builtin_amdgcn_mfma_f32_16x16x32_bf16(a, b, acc, 0, 0, 0);
        }
    }
    int gcol = wid * 16 + m;
    float bias = fw[OFF_T1B + gcol];
#pragma unroll
    for (int r = 0; r < 4; ++r) {
        int row = q * 4 + r;
        float v = leakyf(acc[r] + bias);
        x16[(size_t)(node0 + row) * 64 + gcol] = f2bf(v);
        xt[row][gcol] = v;
    }
    __syncthreads();
    int nl = wid * 4 + q;
    int node = node0 + nl;
    float xv[4];
#pragma unroll
    for (int r = 0; r < 4; ++r) xv[r] = xt[nl][m + 16 * r];
#pragma unroll
    for (int set = 0; set < 3; ++set) {
        const float* gw = fw + OFF_GW1 + set * 128;
        float pd = 0.f, ps = 0.f;
#pragma unroll
        for (int r = 0; r < 4; ++r) {
            int c = m + 16 * r;
            pd = fmaf(xv[r], gw[c], pd);
            ps = fmaf(xv[r], gw[64 + c], ps);
        }
        pd += __shfl_xor(pd, 1); ps += __shfl_xor(ps, 1);
        pd += __shfl_xor(pd, 2); ps += __shfl_xor(ps, 2);
        pd += __shfl_xor(pd, 4); ps += __shfl_xor(ps, 4);
        pd += __shfl_xor(pd, 8); ps += __shfl_xor(ps, 8);
        if (m == 0) {
            float2* p = (float2*)&g1v4[(size_t)set * NN + node];
            *p = make_float2(ps, pd);   // .x=ps, .y=pd
        }
    }
}

// ---------- bucket phase A: partition edges into dst/BW buckets (4B packed recs) ----------
__global__ __launch_bounds__(256) void k_bucketA(const int* __restrict__ s0, const int* __restrict__ s1,
                                                 const int* __restrict__ s2, const int* __restrict__ d0,
                                                 const int* __restrict__ d1, const int* __restrict__ d2,
                                                 const int* __restrict__ rowptr, int* __restrict__ bcur,
                                                 unsigned int* __restrict__ tmp) {
    int set = blockIdx.y;
    const int* ss = set == 0 ? s0 : (set == 1 ? s1 : s2);
    const int* dd = set == 0 ? d0 : (set == 1 ? d1 : d2);
    int t = blockIdx.x * 256 + threadIdx.x;
    if (t >= EE) return;
    int dn_ = dd[t], s_ = ss[t];
    int b = dn_ / BW;
    int base = rowptr[(size_t)set * NN + b * BW];
    int r = atomicAdd(&bcur[set * NB + b], 1);
    tmp[(size_t)set * EE + base + r] = (unsigned)s_ | ((unsigned)(dn_ - b * BW) << 16);
}

// ---------- bucket phase B: LDS ranks + gate coeff -> final CSR (localized writes) ----------
__global__ __launch_bounds__(256) void k_bucketB(const unsigned int* __restrict__ tmp,
                                                 const int* __restrict__ rowptr,
                                                 const float4* __restrict__ g1v4,
                                                 const float* __restrict__ fw,
                                                 int2* __restrict__ csr_se) {
    int b = blockIdx.x, set = blockIdx.y;
    int nb = b * BW;
    if (nb >= NN) return;
    __shared__ float4 gl[BW];
    __shared__ int cur[BW];
    __shared__ int rp[BW];
    int tid = threadIdx.x;
    int ne = NN - nb < BW ? NN - nb : BW;
    if (tid < ne) {
        gl[tid] = g1v4[(size_t)set * NN + nb + tid];
        rp[tid] = rowptr[(size_t)set * NN + nb + tid];
        cur[tid] = 0;
    }
    __syncthreads();
    int start = rp[0];
    int idx_end = nb + BW >= NN ? NN : nb + BW;
    int end = (idx_end == NN) ? EE : rowptr[(size_t)set * NN + idx_end];
    float gbv = fw[OFF_GB1 + set];
    const float4* gv = g1v4 + (size_t)set * NN;
    for (int i = start + tid; i < end; i += 256) {
        unsigned rec = tmp[(size_t)set * EE + i];
        int s = rec & 0xFFFF;
        int dl = rec >> 16;
        float4 gs = gv[s];
        float4 gd = gl[dl];
        float a = tanh_fast(gd.y + gs.x + gbv);
        float e = a * gd.z * gs.z;
        int rank = atomicAdd(&cur[dl], 1);
        csr_se[(size_t)set * EE + rp[dl] + rank] = make_int2(s, __float_as_int(e));
    }
}

// ---------- layer 1: aggregate (precomputed e) + MFMA 64x64 GEMV epilogue ----------
__global__ __launch_bounds__(1024) void k_layer1(const unsigned short* __restrict__ x16,
                                                 const int2* __restrict__ csr_se,
                                                 const int* __restrict__ rowptr,
                                                 const int* __restrict__ deg,
                                                 const unsigned short* __restrict__ wb,
                                                 unsigned short* __restrict__ raw2_16) {
    int set = blockIdx.y;
    __shared__ unsigned short tb[16][72];
    int tid = threadIdx.x, lane = tid & 63, wid = tid >> 6;
    int m = lane & 15, q = lane >> 4;
    int node = blockIdx.x * 16 + wid;
    int start = rfl(rowptr[(size_t)set * NN + node]);
    int cnt = rfl(deg[(size_t)set * NN + node]);
    const int2* cs = csr_se + (size_t)set * EE + start;
    float acc = 0.f;
    int j = 0;
    for (; j + 4 <= cnt; j += 4) {
        int2 e0 = cs[j], e1 = cs[j + 1], e2 = cs[j + 2], e3 = cs[j + 3];
        float v0 = bf2f(x16[(size_t)e0.x * 64 + lane]);
        float v1 = bf2f(x16[(size_t)e1.x * 64 + lane]);
        float v2 = bf2f(x16[(size_t)e2.x * 64 + lane]);
        float v3 = bf2f(x16[(size_t)e3.x * 64 + lane]);
        acc = fmaf(v0, __int_as_float(e0.y), acc);
        acc = fmaf(v1, __int_as_float(e1.y), acc);
        acc = fmaf(v2, __int_as_float(e2.y), acc);
        acc = fmaf(v3, __int_as_float(e3.y), acc);
    }
    for (; j < cnt; ++j) {
        int2 e = cs[j];
        acc = fmaf(bf2f(x16[(size_t)e.x * 64 + lane]), __int_as_float(e.y), acc);
    }
    float t = fmaf(0.3f, bf2f(x16[(size_t)node * 64 + lane]), acc);
    tb[wid][lane] = f2bf(t);
    __syncthreads();
    if (wid < 4) {
        f32x4 c = {0.f, 0.f, 0.f, 0.f};
        const unsigned short* bp = wb + WB_HW1T + set * 4096 + (wid * 16 + m) * 64 + q * 8;
#pragma unroll
        for (int k0 = 0; k0 < 64; k0 += 32) {
            bf16x8 a = *(const bf16x8*)&tb[m][k0 + q * 8];
            bf16x8 b = *(const bf16x8*)(bp + k0);
            c = __builtin_amdgcn_mfma_f32_16x16x32_bf16(a, b, c, 0, 0, 0);
        }
        int gcol = wid * 16 + m;
#pragma unroll
        for (int r = 0; r < 4; ++r) {
            int row = q * 4 + r;
            raw2_16[(size_t)(blockIdx.x * 16 + row) * 192 + set * 64 + gcol] = f2bf(leakyf(c[r]));
        }
    }
}

// ---------- layer-2 gate scalars from raw2 ----------
__global__ __launch_bounds__(1024) void k_p2(const unsigned short* __restrict__ raw2_16,
                                             const float* __restrict__ fw,
                                             float4* __restrict__ g2v4) {
    int tid = threadIdx.x, lane = tid & 63, wid = tid >> 6;
    int node = blockIdx.x * 16 + wid;
    const unsigned short* r = raw2_16 + (size_t)node * 192;
    float v0 = bf2f(r[lane]);
    float v1 = bf2f(r[64 + lane]);
    float v2 = bf2f(r[128 + lane]);
#pragma unroll
    for (int k = 0; k < 3; ++k) {
        const float* g = fw + OFF_GW2 + k * 384;
        float pd = v0 * g[lane] + v1 * g[64 + lane] + v2 * g[128 + lane];
        float ps = v0 * g[192 + lane] + v1 * g[256 + lane] + v2 * g[320 + lane];
#pragma unroll
        for (int mm = 32; mm >= 1; mm >>= 1) { pd += __shfl_xor(pd, mm); ps += __shfl_xor(ps, mm); }
        if (lane == 0) {
            float2* p = (float2*)&g2v4[(size_t)k * NN + node];
            *p = make_float2(ps, pd);
        }
    }
}

// ---------- mark batch nodes, assign compact slots ----------
__global__ __launch_bounds__(256) void k_mark(const int* __restrict__ nodes, int* __restrict__ mark,
                                              int* __restrict__ slotof, int* __restrict__ cnt) {
    int b = blockIdx.x * 256 + threadIdx.x;
    if (b < BB) {
        int n = nodes[b];
        if (atomicCAS(&mark[n], 0, 1) == 0) {
            int s = atomicAdd(cnt, 1);
            slotof[n] = s;
        }
    }
}

// ---------- layer 2 aggregation (marked dst only), inline gate ----------
__global__ __launch_bounds__(1024) void k_layer2(const unsigned short* __restrict__ raw2_16,
                                                 const int2* __restrict__ csr_se,
                                                 const int* __restrict__ rowptr,
                                                 const int* __restrict__ deg,
                                                 const float4* __restrict__ g2v4,
                                                 const float* __restrict__ fw,
                                                 const int* __restrict__ mark,
                                                 const int* __restrict__ slotof,
                                                 float* __restrict__ z2) {
    int set = blockIdx.y;
    int tid = threadIdx.x, lane = tid & 63, wid = tid >> 6;
    int node = blockIdx.x * 16 + wid;
    if (mark[node] == 0) return;
    int start = rfl(rowptr[(size_t)set * NN + node]);
    int cnt = rfl(deg[(size_t)set * NN + node]);
    float4 gn = g2v4[(size_t)set * NN + node];
    float pdv = gn.y, dnd = gn.z;
    float gbv = fw[OFF_GB2 + set];
    const int2* cs = csr_se + (size_t)set * EE + start;
    const float4* gv = g2v4 + (size_t)set * NN;
    float a0 = 0.f, a1 = 0.f, a2 = 0.f;
    for (int j = 0; j < cnt; ++j) {
        int2 se = cs[j];
        int s = se.x;
        float4 g = gv[s];
        float a = tanh_fast(pdv + g.x + gbv);
        float e = a * dnd * g.z;
        const unsigned short* r = raw2_16 + (size_t)s * 192;
        a0 = fmaf(bf2f(r[lane]), e, a0);
        a1 = fmaf(bf2f(r[64 + lane]), e, a1);
        a2 = fmaf(bf2f(r[128 + lane]), e, a2);
    }
    float* z = z2 + (size_t)slotof[node] * 576 + (size_t)set * 192;
    z[lane] = a0; z[64 + lane] = a1; z[128 + lane] = a2;
}

// ---------- final: 16 rows/block, MFMA hw2 + t2 GEMMs, t3 epilogue ----------
__global__ __launch_bounds__(256) void k_final(const int* __restrict__ fl,
                                               const int* __restrict__ nodes,
                                               const int* __restrict__ slotof,
                                               const float* __restrict__ z2,
                                               const unsigned short* __restrict__ raw2_16,
                                               const unsigned short* __restrict__ x16,
                                               const void* __restrict__ hB,
                                               const float* __restrict__ fw,
                                               const unsigned short* __restrict__ wb,
                                               void* __restrict__ outv) {
    __shared__ unsigned short nfb[16][712];   // 704 + 8 pad (bf16)
    __shared__ unsigned short tbb[16][200];   // 192 + 8 pad
    __shared__ float sarr[16][64];
    __shared__ int nd[16], sl[16];
    int tid = threadIdx.x, lane = tid & 63, wid = tid >> 6;
    int m = lane & 15, q = lane >> 4;
    int b0 = blockIdx.x * 16;
    int isf32 = fl[0];
    if (tid < 16) {
        int n = nodes[b0 + tid];
        nd[tid] = n;
        sl[tid] = slotof[n];
    }
    __syncthreads();
    // nf cols 192..447: h ; 448..511: x ; 512..703: raw2
    for (int idx = tid; idx < 16 * 256; idx += 256) {
        int row = idx >> 8, c = idx & 255;
        size_t hi = (size_t)nd[row] * 256 + c;
        nfb[row][192 + c] = isf32 ? f2bf(((const float*)hB)[hi]) : ((const unsigned short*)hB)[hi];
    }
    for (int idx = tid; idx < 16 * 64; idx += 256) {
        int row = idx >> 6, c = idx & 63;
        nfb[row][448 + c] = x16[(size_t)nd[row] * 64 + c];
    }
    for (int idx = tid; idx < 16 * 192; idx += 256) {
        int row = idx / 192, c = idx % 192;
        nfb[row][512 + c] = raw2_16[(size_t)nd[row] * 192 + c];
    }
    for (int set = 0; set < 3; ++set) {
        __syncthreads();
        for (int idx = tid; idx < 16 * 192; idx += 256) {
            int row = idx / 192, c = idx % 192;
            float r2 = bf2f(nfb[row][512 + c]);
            tbb[row][c] = f2bf(fmaf(0.3f, r2, z2[(size_t)sl[row] * 576 + set * 192 + c]));
        }
        __syncthreads();
        f32x4 c4 = {0.f, 0.f, 0.f, 0.f};
        const unsigned short* bp = wb + WB_HW2T + set * 12288 + (wid * 16 + m) * 192 + q * 8;
#pragma unroll
        for (int k0 = 0; k0 < 192; k0 += 32) {
            bf16x8 a = *(const bf16x8*)&tbb[m][k0 + q * 8];
            bf16x8 bf = *(const bf16x8*)(bp + k0);
            c4 = __builtin_amdgcn_mfma_f32_16x16x32_bf16(a, bf, c4, 0, 0, 0);
        }
        int col = wid * 16 + m;
#pragma unroll
        for (int r = 0; r < 4; ++r)
            nfb[q * 4 + r][set * 64 + col] = f2bf(leakyf(c4[r]));
    }
    __syncthreads();
    // t2: [16][704] @ t2w^T -> [16][64]
    f32x4 c4 = {0.f, 0.f, 0.f, 0.f};
    const unsigned short* bp = wb + WB_T2W + (wid * 16 + m) * 704 + q * 8;
#pragma unroll
    for (int k0 = 0; k0 < 704; k0 += 32) {
        bf16x8 a = *(const bf16x8*)&nfb[m][k0 + q * 8];
        bf16x8 bf = *(const bf16x8*)(bp + k0);
        c4 = __builtin_amdgcn_mfma_f32_16x16x32_bf16(a, bf, c4, 0, 0, 0);
    }
    int col = wid * 16 + m;
    float bias = fw[OFF_T2B + col];
#pragma unroll
    for (int r = 0; r < 4; ++r) {
        int row = q * 4 + r;
        float sv = leakyf(c4[r] + bias);
        sarr[row][col] = sv;
        size_t oi = 8192 + (size_t)(b0 + row) * 64 + col;
        if (isf32) ((float*)outv)[oi] = sv;
        else ((unsigned short*)outv)[oi] = f2bf(sv);
    }
    __syncthreads();
    if (tid < 32) {
        int row = tid >> 1, oc = tid & 1;
        float acc = fw[OFF_T3B + oc];
        const float* tw = fw + OFF_T3W + oc * 64;
#pragma unroll 8
        for (int c = 0; c < 64; ++c) acc = fmaf(sarr[row][c], tw[c], acc);
        size_t oi = (size_t)(b0 + row) * 2 + oc;
        if (isf32) ((float*)outv)[oi] = acc;
        else ((unsigned short*)outv)[oi] = f2bf(acc);
    }
}

extern "C" void kernel_launch(void* const* d_in, const int* in_sizes, int n_in,
                              void* d_out, int out_size, void* d_ws, size_t ws_size,
                              hipStream_t stream) {
    const void* h = d_in[0];
    const int* src1 = (const int*)d_in[1];
    const int* dst1 = (const int*)d_in[2];
    const int* src2 = (const int*)d_in[3];
    const int* dst2 = (const int*)d_in[4];
    const int* src3 = (const int*)d_in[5];
    const int* dst3 = (const int*)d_in[6];
    const int* nodes = (const int*)d_in[7];

    char* w = (char*)d_ws;
    size_t off = 0;
    auto carve = [&](size_t bytes) -> void* {
        void* p = w + off;
        off += (bytes + 255) & ~(size_t)255;
        return p;
    };
    int* flag = (int*)carve(256);
    int* deg = (int*)carve((size_t)3 * NN * 4);
    int* rowptr = (int*)carve((size_t)3 * NN * 4);
    int* bsum = (int*)carve((size_t)3 * 64 * 4);
    int* bcur = (int*)carve((size_t)3 * NB * 4);
    float4* g1v4 = (float4*)carve((size_t)3 * NN * 16);
    float4* g2v4 = (float4*)carve((size_t)3 * NN * 16);
    unsigned int* tmp = (unsigned int*)carve((size_t)3 * EE * 4);
    int2* csr_se = (int2*)carve((size_t)3 * EE * 8);
    float* fw = (float*)carve((size_t)WTOT * 4);
    unsigned short* wb = (unsigned short*)carve((size_t)WB_TOT * 2);
    unsigned short* x16 = (unsigned short*)carve((size_t)NN * 64 * 2);
    unsigned short* raw2_16 = (unsigned short*)carve((size_t)NN * 192 * 2);
    int* mark = (int*)carve((size_t)NN * 4);
    int* slotof = (int*)carve((size_t)NN * 4);
    int* cntp = (int*)carve(256);
    float* z2 = (float*)carve((size_t)BB * 576 * 4);

    hipMemsetAsync(deg, 0, (size_t)3 * NN * 4, stream);
    hipMemsetAsync(bcur, 0, (size_t)3 * NB * 4, stream);
    hipMemsetAsync(mark, 0, (size_t)NN * 4, stream);
    hipMemsetAsync(cntp, 0, 4, stream);

    k_sniff<<<1, 64, 0, stream>>>((const unsigned short*)h, flag);
    k_convert<<<(WTOT + 1023) / 1024, 1024, 0, stream>>>(
        flag, d_in[8], d_in[9],
        d_in[10], d_in[16], d_in[22],
        d_in[11], d_in[17], d_in[23],
        d_in[12], d_in[18], d_in[24],
        d_in[13], d_in[19], d_in[25],
        d_in[14], d_in[20], d_in[26],
        d_in[15], d_in[21], d_in[27],
        d_in[28], d_in[29], d_in[30], d_in[31], fw);
    k_convert16<<<(WB_TOT + 255) / 256, 256, 0, stream>>>(flag, d_in[8],
                                                          d_in[12], d_in[18], d_in[24],
                                                          d_in[15], d_in[21], d_in[27],
                                                          d_in[28], wb);

    dim3 ge(3125, 3);
    k_deg<<<ge, 256, 0, stream>>>(dst1, dst2, dst3, deg);
    k_dnorm<<<(3 * NN + 255) / 256, 256, 0, stream>>>(deg, (float*)g1v4, (float*)g2v4);
    dim3 gsc(SCAN_BLK, 3);
    k_scan1<<<gsc, 256, 0, stream>>>(deg, rowptr, bsum);
    k_scan2<<<3, 64, 0, stream>>>(bsum);
    k_scan3<<<gsc, 256, 0, stream>>>(rowptr, bsum);

    k_input<<<3125, 256, 0, stream>>>(flag, h, wb, fw, x16, g1v4);
    k_bucketA<<<ge, 256, 0, stream>>>(src1, src2, src3, dst1, dst2, dst3, rowptr, bcur, tmp);
    dim3 gb(NB, 3);
    k_bucketB<<<gb, 256, 0, stream>>>(tmp, rowptr, g1v4, fw, csr_se);

    dim3 gl(3125, 3);
    k_layer1<<<gl, 1024, 0, stream>>>(x16, csr_se, rowptr, deg, wb, raw2_16);
    k_p2<<<3125, 1024, 0, stream>>>(raw2_16, fw, g2v4);
    k_mark<<<(BB + 255) / 256, 256, 0, stream>>>(nodes, mark, slotof, cntp);
    k_layer2<<<gl, 1024, 0, stream>>>(raw2_16, csr_se, rowptr, deg, g2v4, fw, mark, slotof, z2);
    k_final<<<BB / 16, 256, 0, stream>>>(flag, nodes, slotof, z2, raw2_16, x16, h, fw, wb, d_out);
}

// Round 5
// 631.758 us; speedup vs baseline: 1.7190x; 1.7190x over previous
//
#include <hip/hip_runtime.h>

#define NN 50000
#define EE 800000
#define BB 4096
#define SCAN_BLK 49   // ceil(50000/1024)
#define SLW 6250      // dst-slice width (8 slices)

// f32 weight-table offsets (elements)
#define OFF_T1W 0
#define OFF_T1B 16384
#define OFF_GW1 16448
#define OFF_GB1 16832
#define OFF_HW1 16848
#define OFF_GW2 29136
#define OFF_GB2 30288
#define OFF_HW2 30304
#define OFF_T2W 67168
#define OFF_T2B 112224
#define OFF_T3W 112288
#define OFF_T3B 112416
#define WTOT    112418

// bf16 weight table (MFMA B-operands)
#define WB_T1W  0        // t1w native [64][256]
#define WB_HW1T 16384    // 3 x hw1^T [64][64]
#define WB_HW2T 28672    // 3 x hw2^T [64][192]
#define WB_T2W  65536    // t2w native [64][704]
#define WB_TOT  110592

typedef __attribute__((ext_vector_type(8))) short bf16x8;
typedef __attribute__((ext_vector_type(4))) float f32x4;

__device__ __forceinline__ float bf2f(unsigned short u) {
    return __uint_as_float(((unsigned int)u) << 16);
}
__device__ __forceinline__ unsigned short f2bf(float f) {
    unsigned int u = __float_as_uint(f);
    u = (u + 0x7fffu + ((u >> 16) & 1u)) >> 16;
    return (unsigned short)u;
}
__device__ __forceinline__ float leakyf(float v) { return v >= 0.f ? v : 0.3f * v; }
__device__ __forceinline__ float tanh_fast(float v) {
    float e = __expf(2.f * v);
    return 1.f - 2.f / (e + 1.f);
}
__device__ __forceinline__ int rfl(int v) { return __builtin_amdgcn_readfirstlane(v); }

// ---------- dtype sniffer: 0 = bf16, 1 = f32 ----------
__global__ void k_sniff(const unsigned short* __restrict__ hs, int* __restrict__ flag) {
    int lane = threadIdx.x;
    unsigned short s = hs[2 * lane];
    int ef = (s >> 7) & 0xFF;
    unsigned long long m = __ballot(ef >= 100 && ef <= 132);
    if (lane == 0) flag[0] = (__popcll(m) >= 40) ? 0 : 1;
}

// ---------- convert all weight tensors to one f32 table ----------
__global__ __launch_bounds__(1024) void k_convert(
    const int* __restrict__ fl,
    const void* t1w, const void* t1b,
    const void* gw1a, const void* gw1b, const void* gw1c,
    const void* gb1a, const void* gb1b, const void* gb1c,
    const void* hw1a, const void* hw1b, const void* hw1c,
    const void* gw2a, const void* gw2b, const void* gw2c,
    const void* gb2a, const void* gb2b, const void* gb2c,
    const void* hw2a, const void* hw2b, const void* hw2c,
    const void* t2w, const void* t2b, const void* t3w, const void* t3b,
    float* __restrict__ fw) {
    const int starts[24] = {0, 16384, 16448, 16576, 16704, 16832, 16833, 16834,
                            16848, 20944, 25040, 29136, 29520, 29904, 30288, 30289, 30290,
                            30304, 42592, 54880, 67168, 112224, 112288, 112416};
    const int cnts[24] = {16384, 64, 128, 128, 128, 1, 1, 1, 4096, 4096, 4096,
                          384, 384, 384, 1, 1, 1, 12288, 12288, 12288, 45056, 64, 128, 2};
    const void* sp[24] = {t1w, t1b, gw1a, gw1b, gw1c, gb1a, gb1b, gb1c, hw1a, hw1b, hw1c,
                          gw2a, gw2b, gw2c, gb2a, gb2b, gb2c, hw2a, hw2b, hw2c, t2w, t2b, t3w, t3b};
    int isf32 = fl[0];
    int idx = blockIdx.x * 1024 + threadIdx.x;
    if (idx >= WTOT) return;
    float v = 0.f;
#pragma unroll
    for (int k = 0; k < 24; ++k) {
        int lo = idx - starts[k];
        if (lo >= 0 && lo < cnts[k])
            v = isf32 ? ((const float*)sp[k])[lo] : bf2f(((const unsigned short*)sp[k])[lo]);
    }
    fw[idx] = v;
}

// ---------- bf16 weight table: t1w, hw1^T, hw2^T, t2w ----------
__global__ __launch_bounds__(256) void k_convert16(const int* __restrict__ fl, const void* t1w,
                                                   const void* hw1a, const void* hw1b, const void* hw1c,
                                                   const void* hw2a, const void* hw2b, const void* hw2c,
                                                   const void* t2w, unsigned short* __restrict__ wb) {
    int idx = blockIdx.x * 256 + threadIdx.x;
    if (idx >= WB_TOT) return;
    int isf32 = fl[0];
    const void* p;
    int srci;
    if (idx < WB_HW1T) {
        p = t1w; srci = idx;
    } else if (idx < WB_HW2T) {
        int rel = idx - WB_HW1T;
        int set = rel >> 12, r2 = rel & 4095;
        int jj = r2 >> 6, kk = r2 & 63;          // hw1T[j][k] = hw1[k][j], [64][64]
        p = set == 0 ? hw1a : (set == 1 ? hw1b : hw1c);
        srci = kk * 64 + jj;
    } else if (idx < WB_T2W) {
        int rel = idx - WB_HW2T;
        int set = rel / 12288, r2 = rel % 12288;
        int n = r2 / 192, k = r2 % 192;          // hw2T[n][k] = hw2[k][n], hw2 [192][64]
        p = set == 0 ? hw2a : (set == 1 ? hw2b : hw2c);
        srci = k * 64 + n;
    } else {
        p = t2w; srci = idx - WB_T2W;            // t2w native [64][704]
    }
    wb[idx] = isf32 ? f2bf(((const float*)p)[srci]) : ((const unsigned short*)p)[srci];
}

// ---------- degree count ----------
__global__ __launch_bounds__(256) void k_deg(const int* __restrict__ d0, const int* __restrict__ d1,
                                             const int* __restrict__ d2, int* __restrict__ deg) {
    int set = blockIdx.y;
    const int* dd = set == 0 ? d0 : (set == 1 ? d1 : d2);
    int t = blockIdx.x * 256 + threadIdx.x;
    if (t < EE) atomicAdd(&deg[(size_t)set * NN + dd[t]], 1);
}

// ---------- d into .z of per-node float4 packs (x=ps, y=pd, z=d) ----------
__global__ __launch_bounds__(256) void k_dnorm(const int* __restrict__ deg, float* __restrict__ g1,
                                               float* __restrict__ g2) {
    int t = blockIdx.x * 256 + threadIdx.x;
    if (t < 3 * NN) {
        int g = deg[t];
        float v = g > 0 ? rsqrtf((float)g) : 0.f;
        g1[(size_t)t * 4 + 2] = v;
        g2[(size_t)t * 4 + 2] = v;
    }
}

// ---------- hierarchical exclusive scan ----------
__global__ __launch_bounds__(256) void k_scan1(const int* __restrict__ deg, int* __restrict__ rowptr,
                                               int* __restrict__ bsum) {
    int set = blockIdx.y;
    const int* dg = deg + (size_t)set * NN;
    int* rp = rowptr + (size_t)set * NN;
    __shared__ int sh[256];
    int tid = threadIdx.x;
    int base = blockIdx.x * 1024 + tid * 4;
    int v[4]; int s = 0;
#pragma unroll
    for (int c = 0; c < 4; ++c) { int idx = base + c; v[c] = (idx < NN) ? dg[idx] : 0; s += v[c]; }
    sh[tid] = s;
    __syncthreads();
    for (int off = 1; off < 256; off <<= 1) {
        int t = 0;
        if (tid >= off) t = sh[tid - off];
        __syncthreads();
        if (tid >= off) sh[tid] += t;
        __syncthreads();
    }
    int run = sh[tid] - s;
#pragma unroll
    for (int c = 0; c < 4; ++c) { int idx = base + c; if (idx < NN) rp[idx] = run; run += v[c]; }
    if (tid == 255) bsum[set * SCAN_BLK + blockIdx.x] = sh[255];
}

__global__ void k_scan2(int* __restrict__ bsum) {
    int set = blockIdx.x;
    int* b = bsum + set * SCAN_BLK;
    if (threadIdx.x == 0) {
        int acc = 0;
        for (int i = 0; i < SCAN_BLK; ++i) { int t = b[i]; b[i] = acc; acc += t; }
    }
}

__global__ __launch_bounds__(256) void k_scan3(int* __restrict__ rowptr, int* __restrict__ cursor,
                                               const int* __restrict__ bsum) {
    int set = blockIdx.y;
    int add = bsum[set * SCAN_BLK + blockIdx.x];
    int base = blockIdx.x * 1024 + threadIdx.x * 4;
    int* rp = rowptr + (size_t)set * NN;
    int* cur = cursor + (size_t)set * NN;
#pragma unroll
    for (int c = 0; c < 4; ++c) {
        int idx = base + c;
        if (idx < NN) { int vv = rp[idx] + add; rp[idx] = vv; cur[idx] = vv; }
    }
}

// ---------- input transform via MFMA: x = leaky(h @ t1w^T + b), fused p1 gate dots ----------
__global__ __launch_bounds__(256) void k_input(const int* __restrict__ fl,
                                               const void* __restrict__ hB,
                                               const unsigned short* __restrict__ wb,
                                               const float* __restrict__ fw,
                                               unsigned short* __restrict__ x16,
                                               float4* __restrict__ g1v4) {
    __shared__ float xt[16][65];
    int tid = threadIdx.x, lane = tid & 63, wid = tid >> 6;
    int m = lane & 15, q = lane >> 4;
    int node0 = blockIdx.x * 16;
    int isf32 = fl[0];
    f32x4 acc = {0.f, 0.f, 0.f, 0.f};
    const unsigned short* bsrc = wb + WB_T1W + ((size_t)(wid * 16 + m)) * 256 + q * 8;
    if (isf32) {
        const float* ap = (const float*)hB + (size_t)(node0 + m) * 256 + q * 8;
        for (int k0 = 0; k0 < 256; k0 += 32) {
            float4 f0 = *(const float4*)(ap + k0);
            float4 f1 = *(const float4*)(ap + k0 + 4);
            bf16x8 a;
            a[0] = (short)f2bf(f0.x); a[1] = (short)f2bf(f0.y);
            a[2] = (short)f2bf(f0.z); a[3] = (short)f2bf(f0.w);
            a[4] = (short)f2bf(f1.x); a[5] = (short)f2bf(f1.y);
            a[6] = (short)f2bf(f1.z); a[7] = (short)f2bf(f1.w);
            bf16x8 b = *(const bf16x8*)(bsrc + k0);
            acc = __builtin_amdgcn_mfma_f32_16x16x32_bf16(a, b, acc, 0, 0, 0);
        }
    } else {
        const unsigned short* ap = (const unsigned short*)hB + (size_t)(node0 + m) * 256 + q * 8;
        for (int k0 = 0; k0 < 256; k0 += 32) {
            bf16x8 a = *(const bf16x8*)(ap + k0);
            bf16x8 b = *(const bf16x8*)(bsrc + k0);
            acc = __builtin_amdgcn_mfma_f32_16x16x32_bf16(a, b, acc, 0, 0, 0);
        }
    }
    int gcol = wid * 16 + m;
    float bias = fw[OFF_T1B + gcol];
#pragma unroll
    for (int r = 0; r < 4; ++r) {
        int row = q * 4 + r;
        float v = leakyf(acc[r] + bias);
        x16[(size_t)(node0 + row) * 64 + gcol] = f2bf(v);
        xt[row][gcol] = v;
    }
    __syncthreads();
    int nl = wid * 4 + q;
    int node = node0 + nl;
    float xv[4];
#pragma unroll
    for (int r = 0; r < 4; ++r) xv[r] = xt[nl][m + 16 * r];
#pragma unroll
    for (int set = 0; set < 3; ++set) {
        const float* gw = fw + OFF_GW1 + set * 128;
        float pd = 0.f, ps = 0.f;
#pragma unroll
        for (int r = 0; r < 4; ++r) {
            int c = m + 16 * r;
            pd = fmaf(xv[r], gw[c], pd);
            ps = fmaf(xv[r], gw[64 + c], ps);
        }
        pd += __shfl_xor(pd, 1); ps += __shfl_xor(ps, 1);
        pd += __shfl_xor(pd, 2); ps += __shfl_xor(ps, 2);
        pd += __shfl_xor(pd, 4); ps += __shfl_xor(ps, 4);
        pd += __shfl_xor(pd, 8); ps += __shfl_xor(ps, 8);
        if (m == 0) {
            float2* p = (float2*)&g1v4[(size_t)set * NN + node];
            *p = make_float2(ps, pd);   // .x=ps, .y=pd
        }
    }
}

// ---------- sliced scatter: slice s handles dst in [s*SLW,(s+1)*SLW); fused gate coeff ----------
// blockIdx.x & 7 = slice (round-robin -> XCD-local CSR writes); per-node cursor atomics.
__global__ __launch_bounds__(256) void k_scatter(const int* __restrict__ s0, const int* __restrict__ s1,
                                                 const int* __restrict__ s2, const int* __restrict__ d0,
                                                 const int* __restrict__ d1, const int* __restrict__ d2,
                                                 int* __restrict__ cursor,
                                                 const float4* __restrict__ g1v4,
                                                 const float* __restrict__ fw,
                                                 int2* __restrict__ csr_se) {
    int set = blockIdx.y;
    const int* ss = set == 0 ? s0 : (set == 1 ? s1 : s2);
    const int* dd = set == 0 ? d0 : (set == 1 ? d1 : d2);
    int slice = blockIdx.x & 7;
    int sub = blockIdx.x >> 3;            // 0..99
    int lo = slice * SLW, hi = lo + SLW;
    float gbv = fw[OFF_GB1 + set];
    const float4* gv = g1v4 + (size_t)set * NN;
    int* cur = cursor + (size_t)set * NN;
    int2* cse = csr_se + (size_t)set * EE;
    for (int t = sub * 256 + threadIdx.x; t < EE; t += 100 * 256) {
        int dn_ = dd[t];
        if (dn_ < lo || dn_ >= hi) continue;
        int s_ = ss[t];
        float4 gd = gv[dn_];
        float4 gs = gv[s_];
        float a = tanh_fast(gd.y + gs.x + gbv);
        float e = a * gd.z * gs.z;
        int pos = atomicAdd(&cur[dn_], 1);
        cse[pos] = make_int2(s_, __float_as_int(e));
    }
}

// ---------- layer 1: aggregate (precomputed e) + MFMA 64x64 GEMV epilogue ----------
__global__ __launch_bounds__(1024) void k_layer1(const unsigned short* __restrict__ x16,
                                                 const int2* __restrict__ csr_se,
                                                 const int* __restrict__ rowptr,
                                                 const int* __restrict__ deg,
                                                 const unsigned short* __restrict__ wb,
                                                 unsigned short* __restrict__ raw2_16) {
    int set = blockIdx.y;
    __shared__ unsigned short tb[16][72];
    int tid = threadIdx.x, lane = tid & 63, wid = tid >> 6;
    int m = lane & 15, q = lane >> 4;
    int node = blockIdx.x * 16 + wid;
    int start = rfl(rowptr[(size_t)set * NN + node]);
    int cnt = rfl(deg[(size_t)set * NN + node]);
    const int2* cs = csr_se + (size_t)set * EE + start;
    float acc = 0.f;
    int j = 0;
    for (; j + 4 <= cnt; j += 4) {
        int2 e0 = cs[j], e1 = cs[j + 1], e2 = cs[j + 2], e3 = cs[j + 3];
        float v0 = bf2f(x16[(size_t)e0.x * 64 + lane]);
        float v1 = bf2f(x16[(size_t)e1.x * 64 + lane]);
        float v2 = bf2f(x16[(size_t)e2.x * 64 + lane]);
        float v3 = bf2f(x16[(size_t)e3.x * 64 + lane]);
        acc = fmaf(v0, __int_as_float(e0.y), acc);
        acc = fmaf(v1, __int_as_float(e1.y), acc);
        acc = fmaf(v2, __int_as_float(e2.y), acc);
        acc = fmaf(v3, __int_as_float(e3.y), acc);
    }
    for (; j < cnt; ++j) {
        int2 e = cs[j];
        acc = fmaf(bf2f(x16[(size_t)e.x * 64 + lane]), __int_as_float(e.y), acc);
    }
    float t = fmaf(0.3f, bf2f(x16[(size_t)node * 64 + lane]), acc);
    tb[wid][lane] = f2bf(t);
    __syncthreads();
    if (wid < 4) {
        f32x4 c = {0.f, 0.f, 0.f, 0.f};
        const unsigned short* bp = wb + WB_HW1T + set * 4096 + (wid * 16 + m) * 64 + q * 8;
#pragma unroll
        for (int k0 = 0; k0 < 64; k0 += 32) {
            bf16x8 a = *(const bf16x8*)&tb[m][k0 + q * 8];
            bf16x8 b = *(const bf16x8*)(bp + k0);
            c = __builtin_amdgcn_mfma_f32_16x16x32_bf16(a, b, c, 0, 0, 0);
        }
        int gcol = wid * 16 + m;
#pragma unroll
        for (int r = 0; r < 4; ++r) {
            int row = q * 4 + r;
            raw2_16[(size_t)(blockIdx.x * 16 + row) * 192 + set * 64 + gcol] = f2bf(leakyf(c[r]));
        }
    }
}

// ---------- layer-2 gate scalars from raw2 ----------
__global__ __launch_bounds__(1024) void k_p2(const unsigned short* __restrict__ raw2_16,
                                             const float* __restrict__ fw,
                                             float4* __restrict__ g2v4) {
    int tid = threadIdx.x, lane = tid & 63, wid = tid >> 6;
    int node = blockIdx.x * 16 + wid;
    const unsigned short* r = raw2_16 + (size_t)node * 192;
    float v0 = bf2f(r[lane]);
    float v1 = bf2f(r[64 + lane]);
    float v2 = bf2f(r[128 + lane]);
#pragma unroll
    for (int k = 0; k < 3; ++k) {
        const float* g = fw + OFF_GW2 + k * 384;
        float pd = v0 * g[lane] + v1 * g[64 + lane] + v2 * g[128 + lane];
        float ps = v0 * g[192 + lane] + v1 * g[256 + lane] + v2 * g[320 + lane];
#pragma unroll
        for (int mm = 32; mm >= 1; mm >>= 1) { pd += __shfl_xor(pd, mm); ps += __shfl_xor(ps, mm); }
        if (lane == 0) {
            float2* p = (float2*)&g2v4[(size_t)k * NN + node];
            *p = make_float2(ps, pd);
        }
    }
}

// ---------- mark batch nodes, assign compact slots, build slot->node list ----------
__global__ __launch_bounds__(256) void k_mark(const int* __restrict__ nodes, int* __restrict__ mark,
                                              int* __restrict__ slotof, int* __restrict__ slotnode,
                                              int* __restrict__ cnt) {
    int b = blockIdx.x * 256 + threadIdx.x;
    if (b < BB) {
        int n = nodes[b];
        if (atomicCAS(&mark[n], 0, 1) == 0) {
            int s = atomicAdd(cnt, 1);
            slotof[n] = s;
            slotnode[s] = n;
        }
    }
}

// ---------- layer 2 aggregation over compact slot list, inline gate ----------
__global__ __launch_bounds__(1024) void k_layer2(const unsigned short* __restrict__ raw2_16,
                                                 const int2* __restrict__ csr_se,
                                                 const int* __restrict__ rowptr,
                                                 const int* __restrict__ deg,
                                                 const float4* __restrict__ g2v4,
                                                 const float* __restrict__ fw,
                                                 const int* __restrict__ slotnode,
                                                 const int* __restrict__ cntp,
                                                 float* __restrict__ z2) {
    int set = blockIdx.y;
    int tid = threadIdx.x, lane = tid & 63, wid = tid >> 6;
    int slot = blockIdx.x * 16 + wid;
    if (slot >= cntp[0]) return;
    int node = rfl(slotnode[slot]);
    int start = rfl(rowptr[(size_t)set * NN + node]);
    int cnt = rfl(deg[(size_t)set * NN + node]);
    float4 gn = g2v4[(size_t)set * NN + node];
    float pdv = gn.y, dnd = gn.z;
    float gbv = fw[OFF_GB2 + set];
    const int2* cs = csr_se + (size_t)set * EE + start;
    const float4* gv = g2v4 + (size_t)set * NN;
    float a0 = 0.f, a1 = 0.f, a2 = 0.f;
    for (int j = 0; j < cnt; ++j) {
        int2 se = cs[j];
        int s = se.x;
        float4 g = gv[s];
        float a = tanh_fast(pdv + g.x + gbv);
        float e = a * dnd * g.z;
        const unsigned short* r = raw2_16 + (size_t)s * 192;
        a0 = fmaf(bf2f(r[lane]), e, a0);
        a1 = fmaf(bf2f(r[64 + lane]), e, a1);
        a2 = fmaf(bf2f(r[128 + lane]), e, a2);
    }
    float* z = z2 + (size_t)slot * 576 + (size_t)set * 192;
    z[lane] = a0; z[64 + lane] = a1; z[128 + lane] = a2;
}

// ---------- final: 16 rows/block, MFMA hw2 + t2 GEMMs, t3 epilogue ----------
__global__ __launch_bounds__(256) void k_final(const int* __restrict__ fl,
                                               const int* __restrict__ nodes,
                                               const int* __restrict__ slotof,
                                               const float* __restrict__ z2,
                                               const unsigned short* __restrict__ raw2_16,
                                               const unsigned short* __restrict__ x16,
                                               const void* __restrict__ hB,
                                               const float* __restrict__ fw,
                                               const unsigned short* __restrict__ wb,
                                               void* __restrict__ outv) {
    __shared__ unsigned short nfb[16][712];   // 704 + 8 pad (bf16)
    __shared__ unsigned short tbb[16][200];   // 192 + 8 pad
    __shared__ float sarr[16][64];
    __shared__ int nd[16], sl[16];
    int tid = threadIdx.x, lane = tid & 63, wid = tid >> 6;
    int m = lane & 15, q = lane >> 4;
    int b0 = blockIdx.x * 16;
    int isf32 = fl[0];
    if (tid < 16) {
        int n = nodes[b0 + tid];
        nd[tid] = n;
        sl[tid] = slotof[n];
    }
    __syncthreads();
    for (int idx = tid; idx < 16 * 256; idx += 256) {
        int row = idx >> 8, c = idx & 255;
        size_t hi = (size_t)nd[row] * 256 + c;
        nfb[row][192 + c] = isf32 ? f2bf(((const float*)hB)[hi]) : ((const unsigned short*)hB)[hi];
    }
    for (int idx = tid; idx < 16 * 64; idx += 256) {
        int row = idx >> 6, c = idx & 63;
        nfb[row][448 + c] = x16[(size_t)nd[row] * 64 + c];
    }
    for (int idx = tid; idx < 16 * 192; idx += 256) {
        int row = idx / 192, c = idx % 192;
        nfb[row][512 + c] = raw2_16[(size_t)nd[row] * 192 + c];
    }
    for (int set = 0; set < 3; ++set) {
        __syncthreads();
        for (int idx = tid; idx < 16 * 192; idx += 256) {
            int row = idx / 192, c = idx % 192;
            float r2 = bf2f(nfb[row][512 + c]);
            tbb[row][c] = f2bf(fmaf(0.3f, r2, z2[(size_t)sl[row] * 576 + set * 192 + c]));
        }
        __syncthreads();
        f32x4 c4 = {0.f, 0.f, 0.f, 0.f};
        const unsigned short* bp = wb + WB_HW2T + set * 12288 + (wid * 16 + m) * 192 + q * 8;
#pragma unroll
        for (int k0 = 0; k0 < 192; k0 += 32) {
            bf16x8 a = *(const bf16x8*)&tbb[m][k0 + q * 8];
            bf16x8 bf = *(const bf16x8*)(bp + k0);
            c4 = __builtin_amdgcn_mfma_f32_16x16x32_bf16(a, bf, c4, 0, 0, 0);
        }
        int col = wid * 16 + m;
#pragma unroll
        for (int r = 0; r < 4; ++r)
            nfb[q * 4 + r][set * 64 + col] = f2bf(leakyf(c4[r]));
    }
    __syncthreads();
    f32x4 c4 = {0.f, 0.f, 0.f, 0.f};
    const unsigned short* bp = wb + WB_T2W + (wid * 16 + m) * 704 + q * 8;
#pragma unroll
    for (int k0 = 0; k0 < 704; k0 += 32) {
        bf16x8 a = *(const bf16x8*)&nfb[m][k0 + q * 8];
        bf16x8 bf = *(const bf16x8*)(bp + k0);
        c4 = __builtin_amdgcn_mfma_f32_16x16x32_bf16(a, bf, c4, 0, 0, 0);
    }
    int col = wid * 16 + m;
    float bias = fw[OFF_T2B + col];
#pragma unroll
    for (int r = 0; r < 4; ++r) {
        int row = q * 4 + r;
        float sv = leakyf(c4[r] + bias);
        sarr[row][col] = sv;
        size_t oi = 8192 + (size_t)(b0 + row) * 64 + col;
        if (isf32) ((float*)outv)[oi] = sv;
        else ((unsigned short*)outv)[oi] = f2bf(sv);
    }
    __syncthreads();
    if (tid < 32) {
        int row = tid >> 1, oc = tid & 1;
        float acc = fw[OFF_T3B + oc];
        const float* tw = fw + OFF_T3W + oc * 64;
#pragma unroll 8
        for (int c = 0; c < 64; ++c) acc = fmaf(sarr[row][c], tw[c], acc);
        size_t oi = (size_t)(b0 + row) * 2 + oc;
        if (isf32) ((float*)outv)[oi] = acc;
        else ((unsigned short*)outv)[oi] = f2bf(acc);
    }
}

extern "C" void kernel_launch(void* const* d_in, const int* in_sizes, int n_in,
                              void* d_out, int out_size, void* d_ws, size_t ws_size,
                              hipStream_t stream) {
    const void* h = d_in[0];
    const int* src1 = (const int*)d_in[1];
    const int* dst1 = (const int*)d_in[2];
    const int* src2 = (const int*)d_in[3];
    const int* dst2 = (const int*)d_in[4];
    const int* src3 = (const int*)d_in[5];
    const int* dst3 = (const int*)d_in[6];
    const int* nodes = (const int*)d_in[7];

    char* w = (char*)d_ws;
    size_t off = 0;
    auto carve = [&](size_t bytes) -> void* {
        void* p = w + off;
        off += (bytes + 255) & ~(size_t)255;
        return p;
    };
    // deg, mark, cntp carved contiguously -> single memset
    int* flag = (int*)carve(256);
    int* deg = (int*)carve((size_t)3 * NN * 4);
    int* mark = (int*)carve((size_t)NN * 4);
    int* cntp = (int*)carve(256);
    int* rowptr = (int*)carve((size_t)3 * NN * 4);
    int* cursor = (int*)carve((size_t)3 * NN * 4);
    int* bsum = (int*)carve((size_t)3 * 64 * 4);
    float4* g1v4 = (float4*)carve((size_t)3 * NN * 16);
    float4* g2v4 = (float4*)carve((size_t)3 * NN * 16);
    int2* csr_se = (int2*)carve((size_t)3 * EE * 8);
    float* fw = (float*)carve((size_t)WTOT * 4);
    unsigned short* wb = (unsigned short*)carve((size_t)WB_TOT * 2);
    unsigned short* x16 = (unsigned short*)carve((size_t)NN * 64 * 2);
    unsigned short* raw2_16 = (unsigned short*)carve((size_t)NN * 192 * 2);
    int* slotof = (int*)carve((size_t)NN * 4);
    int* slotnode = (int*)carve((size_t)BB * 4);
    float* z2 = (float*)carve((size_t)BB * 576 * 4);

    size_t zbytes = (size_t)((char*)cntp - (char*)deg) + 256;
    hipMemsetAsync(deg, 0, zbytes, stream);

    k_sniff<<<1, 64, 0, stream>>>((const unsigned short*)h, flag);
    k_convert<<<(WTOT + 1023) / 1024, 1024, 0, stream>>>(
        flag, d_in[8], d_in[9],
        d_in[10], d_in[16], d_in[22],
        d_in[11], d_in[17], d_in[23],
        d_in[12], d_in[18], d_in[24],
        d_in[13], d_in[19], d_in[25],
        d_in[14], d_in[20], d_in[26],
        d_in[15], d_in[21], d_in[27],
        d_in[28], d_in[29], d_in[30], d_in[31], fw);
    k_convert16<<<(WB_TOT + 255) / 256, 256, 0, stream>>>(flag, d_in[8],
                                                          d_in[12], d_in[18], d_in[24],
                                                          d_in[15], d_in[21], d_in[27],
                                                          d_in[28], wb);

    dim3 ge(3125, 3);
    k_deg<<<ge, 256, 0, stream>>>(dst1, dst2, dst3, deg);
    k_dnorm<<<(3 * NN + 255) / 256, 256, 0, stream>>>(deg, (float*)g1v4, (float*)g2v4);
    dim3 gsc(SCAN_BLK, 3);
    k_scan1<<<gsc, 256, 0, stream>>>(deg, rowptr, bsum);
    k_scan2<<<3, 64, 0, stream>>>(bsum);
    k_scan3<<<gsc, 256, 0, stream>>>(rowptr, cursor, bsum);

    k_input<<<3125, 256, 0, stream>>>(flag, h, wb, fw, x16, g1v4);
    dim3 gsl(800, 3);   // 8 slices x 100 sub-blocks
    k_scatter<<<gsl, 256, 0, stream>>>(src1, src2, src3, dst1, dst2, dst3, cursor, g1v4, fw, csr_se);

    dim3 gl(3125, 3);
    k_layer1<<<gl, 1024, 0, stream>>>(x16, csr_se, rowptr, deg, wb, raw2_16);
    k_p2<<<3125, 1024, 0, stream>>>(raw2_16, fw, g2v4);
    k_mark<<<(BB + 255) / 256, 256, 0, stream>>>(nodes, mark, slotof, slotnode, cntp);
    dim3 gl2(BB / 16, 3);
    k_layer2<<<gl2, 1024, 0, stream>>>(raw2_16, csr_se, rowptr, deg, g2v4, fw, slotnode, cntp, z2);
    k_final<<<BB / 16, 256, 0, stream>>>(flag, nodes, slotof, z2, raw2_16, x16, h, fw, wb, d_out);
}